// Round 2
// baseline (5163.298 us; speedup 1.0000x reference)
//
#include <hip/hip_runtime.h>
#include <hip/hip_bf16.h>

#define BB   128   // batch
#define TT   512   // seq len
#define II   256   // input dim
#define HH   512   // hidden dim
#define G3   1536  // 3*H

typedef __attribute__((ext_vector_type(8))) short short8;
typedef __attribute__((ext_vector_type(4))) float f32x4;

__device__ __forceinline__ float bf2f(unsigned short u) {
    union { unsigned int u; float f; } p; p.u = ((unsigned int)u) << 16; return p.f;
}
__device__ __forceinline__ unsigned short f2bf(float f) {
    union { float f; unsigned int u; } p; p.f = f;
    unsigned int r = p.u + 0x7fffu + ((p.u >> 16) & 1u);  // RNE
    return (unsigned short)(r >> 16);
}
__device__ __forceinline__ float sigmoidf_fast(float x) {
    return 1.0f / (1.0f + __expf(-x));
}
__device__ __forceinline__ float tanhf_fast(float x) {
    return 1.0f - 2.0f / (1.0f + __expf(2.0f * x));
}

// ---------------------------------------------------------------------------
// Kernel 1: xg[t][b][g] = bf16( x[b,t,:] @ W_ih[g,:] + b_ih[g] )
// Tile: 128 (batch) x 128 (gate cols), K=256 in 8 steps of 32. 256 thr / 4 waves.
// ---------------------------------------------------------------------------
__global__ __launch_bounds__(256) void xgate_gemm(
    const float* __restrict__ x,       // [B,T,I]
    const float* __restrict__ Wih,     // [1536,256]
    const float* __restrict__ bih,     // [1536]
    unsigned short* __restrict__ xg)   // [T,B,1536] bf16
{
    __shared__ unsigned short AS[128][40];  // [b][k] bf16, +8 pad
    __shared__ unsigned short BS[128][40];  // [g][k] bf16

    const int t   = blockIdx.y;
    const int g0  = blockIdx.x * 128;
    const int tid = threadIdx.x;
    const int lane = tid & 63;
    const int w    = tid >> 6;       // 0..3
    const int wr   = w >> 1, wc = w & 1;

    f32x4 acc[4][4];
#pragma unroll
    for (int a = 0; a < 4; ++a)
#pragma unroll
        for (int b = 0; b < 4; ++b) acc[a][b] = (f32x4)(0.0f);

    for (int kk = 0; kk < 8; ++kk) {
        const int k0 = kk * 32;
        // stage A and B (fp32 -> bf16), 1024 float4 slots each, 4 per thread
#pragma unroll
        for (int ii = 0; ii < 4; ++ii) {
            int slot = tid + 256 * ii;       // 0..1023
            int row  = slot >> 3;            // 0..127
            int c4   = slot & 7;             // 0..7
            float4 av = *(const float4*)(x + ((size_t)row * TT + t) * II + k0 + c4 * 4);
            unsigned short* ap = &AS[row][c4 * 4];
            ap[0] = f2bf(av.x); ap[1] = f2bf(av.y); ap[2] = f2bf(av.z); ap[3] = f2bf(av.w);
            float4 bv = *(const float4*)(Wih + (size_t)(g0 + row) * II + k0 + c4 * 4);
            unsigned short* bp = &BS[row][c4 * 4];
            bp[0] = f2bf(bv.x); bp[1] = f2bf(bv.y); bp[2] = f2bf(bv.z); bp[3] = f2bf(bv.w);
        }
        __syncthreads();

        const int kc = (lane >> 4) * 8;
        short8 a[4], b[4];
#pragma unroll
        for (int mi = 0; mi < 4; ++mi)
            a[mi] = *(const short8*)&AS[wr * 64 + mi * 16 + (lane & 15)][kc];
#pragma unroll
        for (int ni = 0; ni < 4; ++ni)
            b[ni] = *(const short8*)&BS[wc * 64 + ni * 16 + (lane & 15)][kc];
#pragma unroll
        for (int mi = 0; mi < 4; ++mi)
#pragma unroll
            for (int ni = 0; ni < 4; ++ni)
                acc[mi][ni] = __builtin_amdgcn_mfma_f32_16x16x32_bf16(a[mi], b[ni], acc[mi][ni], 0, 0, 0);
        __syncthreads();
    }

    // epilogue: D row=(lane>>4)*4+i (batch), col=lane&15 (gate)
#pragma unroll
    for (int ni = 0; ni < 4; ++ni) {
        const int col = wc * 64 + ni * 16 + (lane & 15);
        const float bias = bih[g0 + col];
#pragma unroll
        for (int mi = 0; mi < 4; ++mi) {
#pragma unroll
            for (int i = 0; i < 4; ++i) {
                const int row = wr * 64 + mi * 16 + (lane >> 4) * 4 + i;
                xg[((size_t)t * BB + row) * G3 + g0 + col] = f2bf(acc[mi][ni][i] + bias);
            }
        }
    }
}

// ---------------------------------------------------------------------------
// Kernel 2: GRU recurrence. 128 blocks = 8 groups (of 16 batch rows) x 16
// members (of 32 h-dims). W_hh slice (96 rows x 512) lives in LDS for all 512
// steps. Each step: broadcast h (bf16, global double-buffer) -> MFMA -> gates.
// Group-local sync via agent-scope atomic counter.
// ---------------------------------------------------------------------------
#define NTH2 384  // 6 waves

__global__ __launch_bounds__(NTH2, 1) void gru_scan(
    const unsigned short* __restrict__ xg,   // [T,B,1536] bf16
    const float* __restrict__ Whh,           // [1536,512]
    const float* __restrict__ bhh,           // [1536]
    float* __restrict__ out,                 // [B,H]
    unsigned short* __restrict__ hbuf,       // [2][B][H] bf16
    unsigned int* __restrict__ counters)     // [8 * 16]
{
    extern __shared__ unsigned char lds[];
    unsigned short (*Ws)[520] = (unsigned short(*)[520])lds;                    // [96][520]
    unsigned short (*hS)[520] = (unsigned short(*)[520])(lds + 96 * 520 * 2);   // [16][520]
    float (*hgS)[100]         = (float(*)[100])(lds + (96 + 16) * 520 * 2);     // [16][100]
    float* bhS                = (float*)(lds + (96 + 16) * 520 * 2 + 16 * 100 * 4); // [96]

    const int g   = blockIdx.x & 7;    // group (batch rows 16g..16g+15)
    const int m   = blockIdx.x >> 3;   // member (h dims 32m..32m+31)
    const int tid = threadIdx.x;
    const int lane = tid & 63;
    const int w    = tid >> 6;         // 0..5: n-tile (gate cols 16w..16w+15 of slice)
    unsigned int* cnt = counters + g * 16;

    // ---- init: load W_hh slice (bf16) + b_hh slice into LDS ----
    for (int idx = tid; idx < 96 * 512; idx += NTH2) {
        int lr = idx >> 9, c = idx & 511;
        int grow = (lr >> 5) * HH + m * 32 + (lr & 31);   // gate s = lr>>5
        Ws[lr][c] = f2bf(Whh[(size_t)grow * HH + c]);
    }
    if (tid < 96) {
        int grow = (tid >> 5) * HH + m * 32 + (tid & 31);
        bhS[tid] = bhh[grow];
    }
    __syncthreads();

    // update-phase ownership: elem idx -> (b=idx>>5, j=idx&31); 512 elems, 384 thr
    const int b0 = tid >> 5, j0 = tid & 31;
    const bool has1 = (tid < 128);
    const int idx1 = 384 + tid;
    const int b1 = idx1 >> 5, j1 = idx1 & 31;
    float hreg0 = 0.0f, hreg1 = 0.0f;

    for (int t = 0; t < TT; ++t) {
        // ---- prefetch xg for this step (hides under the spin-wait) ----
        const size_t base = ((size_t)t * BB + g * 16) * (size_t)G3;
        float xr0, xz0, xn0, xr1 = 0.f, xz1 = 0.f, xn1 = 0.f;
        {
            size_t o = base + (size_t)b0 * G3 + m * 32 + j0;
            xr0 = bf2f(xg[o]); xz0 = bf2f(xg[o + 512]); xn0 = bf2f(xg[o + 1024]);
            if (has1) {
                size_t o1 = base + (size_t)b1 * G3 + m * 32 + j1;
                xr1 = bf2f(xg[o1]); xz1 = bf2f(xg[o1 + 512]); xn1 = bf2f(xg[o1 + 1024]);
            }
        }
        // ---- wait: all 16 group members finished step t-1 ----
        if (tid == 0) {
            const unsigned int need = 16u * (unsigned int)t;
            while (__hip_atomic_load(cnt, __ATOMIC_ACQUIRE, __HIP_MEMORY_SCOPE_AGENT) < need)
                __builtin_amdgcn_s_sleep(1);
        }
        __syncthreads();

        // ---- stage h tile (16 x 512 bf16) from hbuf[t&1] ----
        const unsigned short* hsrc = hbuf + ((size_t)(t & 1)) * BB * HH + (size_t)g * 16 * HH;
        for (int idx = tid; idx < 16 * 64; idx += NTH2) {
            int r = idx >> 6, c8 = idx & 63;
            *(uint4*)&hS[r][c8 * 8] = *(const uint4*)(hsrc + (size_t)r * HH + c8 * 8);
        }
        __syncthreads();

        // ---- MFMA: wave w computes 16x16 tile (batch x gate), K=512 ----
        {
            f32x4 acc = (f32x4)(0.0f);
            const int arow = lane & 15;
            const int kc = (lane >> 4) * 8;
            const int brow = w * 16 + (lane & 15);
#pragma unroll
            for (int kk = 0; kk < 16; ++kk) {
                short8 a = *(const short8*)&hS[arow][kk * 32 + kc];
                short8 b = *(const short8*)&Ws[brow][kk * 32 + kc];
                acc = __builtin_amdgcn_mfma_f32_16x16x32_bf16(a, b, acc, 0, 0, 0);
            }
#pragma unroll
            for (int i = 0; i < 4; ++i)
                hgS[(lane >> 4) * 4 + i][w * 16 + (lane & 15)] = acc[i];
        }
        __syncthreads();

        // ---- gate math + state update ----
        const int p2 = (t + 1) & 1;
        unsigned short* hdst = hbuf + (size_t)p2 * BB * HH;
        {
            float hr = hgS[b0][j0]      + bhS[j0];
            float hz = hgS[b0][32 + j0] + bhS[32 + j0];
            float hn = hgS[b0][64 + j0] + bhS[64 + j0];
            float r = sigmoidf_fast(xr0 + hr);
            float z = sigmoidf_fast(xz0 + hz);
            float n = tanhf_fast(xn0 + r * hn);
            hreg0 = (1.0f - z) * n + z * hreg0;
            hdst[(size_t)(g * 16 + b0) * HH + m * 32 + j0] = f2bf(hreg0);
            if (t == TT - 1) out[(size_t)(g * 16 + b0) * HH + m * 32 + j0] = hreg0;
        }
        if (has1) {
            float hr = hgS[b1][j1]      + bhS[j1];
            float hz = hgS[b1][32 + j1] + bhS[32 + j1];
            float hn = hgS[b1][64 + j1] + bhS[64 + j1];
            float r = sigmoidf_fast(xr1 + hr);
            float z = sigmoidf_fast(xz1 + hz);
            float n = tanhf_fast(xn1 + r * hn);
            hreg1 = (1.0f - z) * n + z * hreg1;
            hdst[(size_t)(g * 16 + b1) * HH + m * 32 + j1] = f2bf(hreg1);
            if (t == TT - 1) out[(size_t)(g * 16 + b1) * HH + m * 32 + j1] = hreg1;
        }
        __syncthreads();   // drains all global h stores (vmcnt) before the flag

        // ---- signal completion of step t ----
        if (t < TT - 1) {
            if (tid == 0) {
                __threadfence();  // agent-scope release: flush dirty L2 lines
                __hip_atomic_fetch_add(cnt, 1u, __ATOMIC_RELEASE, __HIP_MEMORY_SCOPE_AGENT);
            }
        }
    }
}

// ---------------------------------------------------------------------------
extern "C" void kernel_launch(void* const* d_in, const int* in_sizes, int n_in,
                              void* d_out, int out_size, void* d_ws, size_t ws_size,
                              hipStream_t stream) {
    const float* x   = (const float*)d_in[0];
    const float* Wih = (const float*)d_in[1];
    const float* Whh = (const float*)d_in[2];
    const float* bih = (const float*)d_in[3];
    const float* bhh = (const float*)d_in[4];
    float* out = (float*)d_out;

    const size_t XG_BYTES = (size_t)TT * BB * G3 * 2;          // 192 MiB bf16
    unsigned short* xg       = (unsigned short*)d_ws;
    unsigned short* hbuf     = (unsigned short*)((char*)d_ws + XG_BYTES);
    const size_t HBUF_BYTES  = (size_t)2 * BB * HH * 2;        // 256 KiB
    unsigned int* counters   = (unsigned int*)((char*)d_ws + XG_BYTES + HBUF_BYTES);
    const size_t CNT_BYTES   = 8 * 16 * sizeof(unsigned int);

    // zero h double-buffer + group counters (ws is poisoned before every launch)
    hipMemsetAsync((char*)d_ws + XG_BYTES, 0, HBUF_BYTES + CNT_BYTES, stream);

    dim3 g1(G3 / 128, TT);
    xgate_gemm<<<g1, 256, 0, stream>>>(x, Wih, bih, xg);

    const int LDS2 = (96 + 16) * 520 * 2 + 16 * 100 * 4 + 96 * 4;  // 123264 B
    hipFuncSetAttribute((const void*)gru_scan,
                        hipFuncAttributeMaxDynamicSharedMemorySize, LDS2);
    gru_scan<<<128, NTH2, LDS2, stream>>>(xg, Whh, bhh, out, hbuf, counters);
}

// Round 3
// 3394.350 us; speedup vs baseline: 1.5211x; 1.5211x over previous
//
#include <hip/hip_runtime.h>
#include <hip/hip_bf16.h>

#define BB   128   // batch
#define TT   512   // seq len
#define II   256   // input dim
#define HH   512   // hidden dim
#define G3   1536  // 3*H

typedef __attribute__((ext_vector_type(8))) short short8;
typedef __attribute__((ext_vector_type(4))) float f32x4;

__device__ __forceinline__ float bf2f(unsigned short u) {
    union { unsigned int u; float f; } p; p.u = ((unsigned int)u) << 16; return p.f;
}
__device__ __forceinline__ unsigned short f2bf(float f) {
    union { float f; unsigned int u; } p; p.f = f;
    unsigned int r = p.u + 0x7fffu + ((p.u >> 16) & 1u);  // RNE
    return (unsigned short)(r >> 16);
}
__device__ __forceinline__ float sigmoidf_fast(float x) {
    return 1.0f / (1.0f + __expf(-x));
}
__device__ __forceinline__ float tanhf_fast(float x) {
    return 1.0f - 2.0f / (1.0f + __expf(2.0f * x));
}

// ---------------------------------------------------------------------------
// Kernel 1: xg[t][b][g] = bf16( x[b,t,:] @ W_ih[g,:] + b_ih[g] )   (unchanged)
// ---------------------------------------------------------------------------
__global__ __launch_bounds__(256) void xgate_gemm(
    const float* __restrict__ x,       // [B,T,I]
    const float* __restrict__ Wih,     // [1536,256]
    const float* __restrict__ bih,     // [1536]
    unsigned short* __restrict__ xg)   // [T,B,1536] bf16
{
    __shared__ unsigned short AS[128][40];
    __shared__ unsigned short BS[128][40];

    const int t   = blockIdx.y;
    const int g0  = blockIdx.x * 128;
    const int tid = threadIdx.x;
    const int lane = tid & 63;
    const int w    = tid >> 6;
    const int wr   = w >> 1, wc = w & 1;

    f32x4 acc[4][4];
#pragma unroll
    for (int a = 0; a < 4; ++a)
#pragma unroll
        for (int b = 0; b < 4; ++b) acc[a][b] = (f32x4)(0.0f);

    for (int kk = 0; kk < 8; ++kk) {
        const int k0 = kk * 32;
#pragma unroll
        for (int ii = 0; ii < 4; ++ii) {
            int slot = tid + 256 * ii;
            int row  = slot >> 3;
            int c4   = slot & 7;
            float4 av = *(const float4*)(x + ((size_t)row * TT + t) * II + k0 + c4 * 4);
            unsigned short* ap = &AS[row][c4 * 4];
            ap[0] = f2bf(av.x); ap[1] = f2bf(av.y); ap[2] = f2bf(av.z); ap[3] = f2bf(av.w);
            float4 bv = *(const float4*)(Wih + (size_t)(g0 + row) * II + k0 + c4 * 4);
            unsigned short* bp = &BS[row][c4 * 4];
            bp[0] = f2bf(bv.x); bp[1] = f2bf(bv.y); bp[2] = f2bf(bv.z); bp[3] = f2bf(bv.w);
        }
        __syncthreads();

        const int kc = (lane >> 4) * 8;
        short8 a[4], b[4];
#pragma unroll
        for (int mi = 0; mi < 4; ++mi)
            a[mi] = *(const short8*)&AS[wr * 64 + mi * 16 + (lane & 15)][kc];
#pragma unroll
        for (int ni = 0; ni < 4; ++ni)
            b[ni] = *(const short8*)&BS[wc * 64 + ni * 16 + (lane & 15)][kc];
#pragma unroll
        for (int mi = 0; mi < 4; ++mi)
#pragma unroll
            for (int ni = 0; ni < 4; ++ni)
                acc[mi][ni] = __builtin_amdgcn_mfma_f32_16x16x32_bf16(a[mi], b[ni], acc[mi][ni], 0, 0, 0);
        __syncthreads();
    }

#pragma unroll
    for (int ni = 0; ni < 4; ++ni) {
        const int col = wc * 64 + ni * 16 + (lane & 15);
        const float bias = bih[g0 + col];
#pragma unroll
        for (int mi = 0; mi < 4; ++mi) {
#pragma unroll
            for (int i = 0; i < 4; ++i) {
                const int row = wr * 64 + mi * 16 + (lane >> 4) * 4 + i;
                xg[((size_t)t * BB + row) * G3 + g0 + col] = f2bf(acc[mi][ni][i] + bias);
            }
        }
    }
}

// ---------------------------------------------------------------------------
// Kernel 2 v2: GRU recurrence, cheap-coherence version.
// 128 blocks = 8 groups (16 batch rows) x 16 members (32 h-dims).
// Block = 128 threads (2 waves); wave w owns j-dims m*32+w*16 .. +15 and
// computes r,z,n MFMA tiles for them -> gate math entirely in-register.
// W_hh slice in LDS in MFMA-fragment order (conflict-free ds_read_b128).
// h exchange via relaxed agent-scope atomics (sc1, L3-coherent, NO fences).
// Per-member flag word; all lanes poll; store->flag ordered by the
// compiler-emitted s_waitcnt vmcnt(0) before s_barrier in __syncthreads().
// ---------------------------------------------------------------------------
#define NTH2 128

__global__ __launch_bounds__(NTH2, 1) void gru_scan(
    const unsigned short* __restrict__ xg,   // [T,B,1536] bf16
    const float* __restrict__ Whh,           // [1536,512]
    const float* __restrict__ bhh,           // [1536]
    float* __restrict__ out,                 // [B,H]
    unsigned short* __restrict__ hbuf,       // [2][B][H] bf16
    unsigned int* __restrict__ flags)        // [8][16]
{
    extern __shared__ unsigned char lds[];
    unsigned char* Wf = lds;                 // 96 KiB: [tile 0..5][ks 0..15][1024B frag]
    unsigned char* hF = lds + 96 * 1024;     // 16 KiB: [ks 0..15][1024B frag]

    const int g    = blockIdx.x & 7;     // group: batch rows 16g..16g+15
    const int m    = blockIdx.x >> 3;    // member: h dims 32m..32m+31
    const int tid  = threadIdx.x;
    const int lane = tid & 63;
    const int w    = tid >> 6;           // wave 0/1: j half-tile

    // ---- W_hh slice -> LDS, fragment order ----
    // element (gate q, local j jl, k) -> tile tq=q*2+(jl>>4), cell ks=k>>5,
    // lane l=(jl&15)+16*((k>>3)&3), elem e=k&7
    for (int idx = tid; idx < 96 * 256; idx += NTH2) {
        int r  = idx >> 8;               // 0..95
        int q  = r >> 5, jl = r & 31;
        int wv = jl >> 4, c = jl & 15;
        int k  = (idx & 255) << 1;
        int ks = k >> 5, lg = (k >> 3) & 3, e2 = (k & 7) >> 1;
        const float* src = Whh + ((size_t)(q * HH + m * 32 + jl)) * HH + k;
        float2 v = *(const float2*)src;
        unsigned int word = (unsigned int)f2bf(v.x) | ((unsigned int)f2bf(v.y) << 16);
        ((unsigned int*)Wf)[((q * 2 + wv) * 16 + ks) * 256 + (c + 16 * lg) * 4 + e2] = word;
    }
    __syncthreads();

    const int jj = m * 32 + w * 16 + (lane & 15);   // this lane's global j
    const float bhr = bhh[jj];
    const float bhz = bhh[HH + jj];
    const float bhn = bhh[2 * HH + jj];
    const int b0 = (lane >> 4) * 4;                 // first of 4 batch rows

    float hh[4] = {0.0f, 0.0f, 0.0f, 0.0f};        // carried fp32 state

    unsigned int* myflag = flags + g * 16 + m;
    unsigned int* pollp  = flags + g * 16 + (lane & 15);
    unsigned int* hb32   = (unsigned int*)hbuf;

    const unsigned char* hA = hF + lane * 16;
    const unsigned char* w0 = Wf + ((0 * 2 + w) * 16) * 1024 + lane * 16;
    const unsigned char* w1 = Wf + ((1 * 2 + w) * 16) * 1024 + lane * 16;
    const unsigned char* w2 = Wf + ((2 * 2 + w) * 16) * 1024 + lane * 16;

    for (int t = 0; t < TT; ++t) {
        // ---- xg prefetch (latency hides under poll) ----
        const unsigned short* xp = xg + ((size_t)t * BB + g * 16) * G3 + jj;
        float xr[4], xz[4], xn[4];
#pragma unroll
        for (int i = 0; i < 4; ++i) {
            const unsigned short* p = xp + (size_t)(b0 + i) * G3;
            xr[i] = bf2f(p[0]); xz[i] = bf2f(p[HH]); xn[i] = bf2f(p[2 * HH]);
        }

        // ---- poll: all 16 members finished step t-1 (h_t at L3) ----
        if (t > 0) {
            while (true) {
                unsigned int v = __hip_atomic_load(pollp, __ATOMIC_RELAXED, __HIP_MEMORY_SCOPE_AGENT);
                if (__all(v >= (unsigned int)t)) break;
            }
        }

        // ---- stage h tile (16x512 bf16) -> hF in fragment order ----
        {
            const unsigned long long* src = (const unsigned long long*)
                (hbuf + ((size_t)(t & 1) * BB + (size_t)g * 16) * HH);
            unsigned long long* dst = (unsigned long long*)hF;
#pragma unroll
            for (int i = 0; i < 16; ++i) {
                int widx = tid + NTH2 * i;          // 0..2047
                int b  = widx & 15, kq = widx >> 4; // kq = k/4, 0..127
                unsigned long long v = __hip_atomic_load(&src[(size_t)b * 128 + kq],
                                                         __ATOMIC_RELAXED, __HIP_MEMORY_SCOPE_AGENT);
                int ks = kq >> 3, lg = (kq >> 1) & 3, e = kq & 1;
                dst[ks * 128 + (b + 16 * lg) * 2 + e] = v;
            }
        }
        __syncthreads();

        // ---- MFMA: acc[q] = h_tile @ W_q^T for this wave's 16 j-dims ----
        f32x4 aR = (f32x4)(0.0f), aZ = (f32x4)(0.0f), aN = (f32x4)(0.0f);
#pragma unroll
        for (int ks = 0; ks < 16; ++ks) {
            short8 a = *(const short8*)(hA + ks * 1024);
            aR = __builtin_amdgcn_mfma_f32_16x16x32_bf16(a, *(const short8*)(w0 + ks * 1024), aR, 0, 0, 0);
            aZ = __builtin_amdgcn_mfma_f32_16x16x32_bf16(a, *(const short8*)(w1 + ks * 1024), aZ, 0, 0, 0);
            aN = __builtin_amdgcn_mfma_f32_16x16x32_bf16(a, *(const short8*)(w2 + ks * 1024), aN, 0, 0, 0);
        }

        // ---- gates in-register; pack bf16 pairs via shfl; sc1 stores ----
        const unsigned int orow32 = (unsigned int)(((t + 1) & 1) * BB * HH) >> 1;
#pragma unroll
        for (int i = 0; i < 4; ++i) {
            float r = sigmoidf_fast(xr[i] + aR[i] + bhr);
            float z = sigmoidf_fast(xz[i] + aZ[i] + bhz);
            float n = tanhf_fast(xn[i] + r * (aN[i] + bhn));
            hh[i] = (1.0f - z) * n + z * hh[i];
            unsigned int u  = (unsigned int)f2bf(hh[i]);
            unsigned int pv = (unsigned int)__shfl_xor((int)u, 1);
            if ((lane & 1) == 0) {
                unsigned int word = u | (pv << 16);
                unsigned int idx32 = ((unsigned int)(g * 16 + b0 + i) * HH + (unsigned int)jj) >> 1;
                __hip_atomic_store(&hb32[orow32 + idx32], word,
                                   __ATOMIC_RELAXED, __HIP_MEMORY_SCOPE_AGENT);
            }
            if (t == TT - 1)
                out[(size_t)(g * 16 + b0 + i) * HH + jj] = hh[i];
        }

        // __syncthreads drains vmcnt per wave before s_barrier -> all h stores
        // are acked at the coherence point before the flag is issued.
        __syncthreads();
        if (tid == 0)
            __hip_atomic_store(myflag, (unsigned int)(t + 1),
                               __ATOMIC_RELAXED, __HIP_MEMORY_SCOPE_AGENT);
    }
}

// ---------------------------------------------------------------------------
extern "C" void kernel_launch(void* const* d_in, const int* in_sizes, int n_in,
                              void* d_out, int out_size, void* d_ws, size_t ws_size,
                              hipStream_t stream) {
    const float* x   = (const float*)d_in[0];
    const float* Wih = (const float*)d_in[1];
    const float* Whh = (const float*)d_in[2];
    const float* bih = (const float*)d_in[3];
    const float* bhh = (const float*)d_in[4];
    float* out = (float*)d_out;

    const size_t XG_BYTES = (size_t)TT * BB * G3 * 2;          // 192 MiB bf16
    unsigned short* xg       = (unsigned short*)d_ws;
    unsigned short* hbuf     = (unsigned short*)((char*)d_ws + XG_BYTES);
    const size_t HBUF_BYTES  = (size_t)2 * BB * HH * 2;        // 256 KiB
    unsigned int* flags      = (unsigned int*)((char*)d_ws + XG_BYTES + HBUF_BYTES);
    const size_t CNT_BYTES   = 8 * 16 * sizeof(unsigned int);

    hipMemsetAsync((char*)d_ws + XG_BYTES, 0, HBUF_BYTES + CNT_BYTES, stream);

    dim3 g1(G3 / 128, TT);
    xgate_gemm<<<g1, 256, 0, stream>>>(x, Wih, bih, xg);

    const int LDS2 = 96 * 1024 + 16 * 1024;  // 114688 B
    hipFuncSetAttribute((const void*)gru_scan,
                        hipFuncAttributeMaxDynamicSharedMemorySize, LDS2);
    gru_scan<<<128, NTH2, LDS2, stream>>>(xg, Whh, bhh, out, hbuf, flags);
}

// Round 4
// 1839.218 us; speedup vs baseline: 2.8073x; 1.8455x over previous
//
#include <hip/hip_runtime.h>
#include <hip/hip_bf16.h>

#define BB   128   // batch
#define TT   512   // seq len
#define II   256   // input dim
#define HH   512   // hidden dim
#define G3   1536  // 3*H

typedef __attribute__((ext_vector_type(8))) short short8;
typedef __attribute__((ext_vector_type(4))) float f32x4;

__device__ __forceinline__ float bf2f(unsigned short u) {
    union { unsigned int u; float f; } p; p.u = ((unsigned int)u) << 16; return p.f;
}
__device__ __forceinline__ unsigned short f2bf(float f) {
    union { float f; unsigned int u; } p; p.f = f;
    unsigned int r = p.u + 0x7fffu + ((p.u >> 16) & 1u);  // RNE
    return (unsigned short)(r >> 16);
}
__device__ __forceinline__ float sigmoidf_fast(float x) {
    return 1.0f / (1.0f + __expf(-x));
}
__device__ __forceinline__ float tanhf_fast(float x) {
    return 1.0f - 2.0f / (1.0f + __expf(2.0f * x));
}

// ---------------------------------------------------------------------------
// Kernel 1: xg[t][b][g] = bf16( x[b,t,:] @ W_ih[g,:] + b_ih[g] )   (unchanged)
// ---------------------------------------------------------------------------
__global__ __launch_bounds__(256) void xgate_gemm(
    const float* __restrict__ x,       // [B,T,I]
    const float* __restrict__ Wih,     // [1536,256]
    const float* __restrict__ bih,     // [1536]
    unsigned short* __restrict__ xg)   // [T,B,1536] bf16
{
    __shared__ unsigned short AS[128][40];
    __shared__ unsigned short BS[128][40];

    const int t   = blockIdx.y;
    const int g0  = blockIdx.x * 128;
    const int tid = threadIdx.x;
    const int lane = tid & 63;
    const int w    = tid >> 6;
    const int wr   = w >> 1, wc = w & 1;

    f32x4 acc[4][4];
#pragma unroll
    for (int a = 0; a < 4; ++a)
#pragma unroll
        for (int b = 0; b < 4; ++b) acc[a][b] = (f32x4)(0.0f);

    for (int kk = 0; kk < 8; ++kk) {
        const int k0 = kk * 32;
#pragma unroll
        for (int ii = 0; ii < 4; ++ii) {
            int slot = tid + 256 * ii;
            int row  = slot >> 3;
            int c4   = slot & 7;
            float4 av = *(const float4*)(x + ((size_t)row * TT + t) * II + k0 + c4 * 4);
            unsigned short* ap = &AS[row][c4 * 4];
            ap[0] = f2bf(av.x); ap[1] = f2bf(av.y); ap[2] = f2bf(av.z); ap[3] = f2bf(av.w);
            float4 bv = *(const float4*)(Wih + (size_t)(g0 + row) * II + k0 + c4 * 4);
            unsigned short* bp = &BS[row][c4 * 4];
            bp[0] = f2bf(bv.x); bp[1] = f2bf(bv.y); bp[2] = f2bf(bv.z); bp[3] = f2bf(bv.w);
        }
        __syncthreads();

        const int kc = (lane >> 4) * 8;
        short8 a[4], b[4];
#pragma unroll
        for (int mi = 0; mi < 4; ++mi)
            a[mi] = *(const short8*)&AS[wr * 64 + mi * 16 + (lane & 15)][kc];
#pragma unroll
        for (int ni = 0; ni < 4; ++ni)
            b[ni] = *(const short8*)&BS[wc * 64 + ni * 16 + (lane & 15)][kc];
#pragma unroll
        for (int mi = 0; mi < 4; ++mi)
#pragma unroll
            for (int ni = 0; ni < 4; ++ni)
                acc[mi][ni] = __builtin_amdgcn_mfma_f32_16x16x32_bf16(a[mi], b[ni], acc[mi][ni], 0, 0, 0);
        __syncthreads();
    }

#pragma unroll
    for (int ni = 0; ni < 4; ++ni) {
        const int col = wc * 64 + ni * 16 + (lane & 15);
        const float bias = bih[g0 + col];
#pragma unroll
        for (int mi = 0; mi < 4; ++mi) {
#pragma unroll
            for (int i = 0; i < 4; ++i) {
                const int row = wr * 64 + mi * 16 + (lane >> 4) * 4 + i;
                xg[((size_t)t * BB + row) * G3 + g0 + col] = f2bf(acc[mi][ni][i] + bias);
            }
        }
    }
}

// ---------------------------------------------------------------------------
// Kernel 2 v3: tagged-data exchange + W_hh in registers.
// 128 blocks = 8 groups (16 batch rows) x 16 members (32 h-dims).
// Block = 128 threads (2 waves); wave w owns j-dims m*32+w*16..+15; its W
// slice (3 gates x 16 j x 512 k = 192 VGPR/lane) lives in registers.
// h exchange: hbuf64[parity][row][pair] = (tag<<32)|2xbf16, relaxed agent
// atomics. Data IS the flag: consumer polls words until tag==t. Safe because
// parity p is only overwritten with tag t+2 after all members published t+1,
// which proves everyone finished staging h(t) from parity p.
// ---------------------------------------------------------------------------
#define NTH2 128

__global__ __launch_bounds__(NTH2, 1) void gru_scan(
    const unsigned short* __restrict__ xg,    // [T,B,1536] bf16
    const float* __restrict__ Whh,            // [1536,512]
    const float* __restrict__ bhh,            // [1536]
    float* __restrict__ out,                  // [B,H]
    unsigned long long* __restrict__ hb64)    // [2][B][256] tagged pairs
{
    __shared__ unsigned int hF[4096];   // 16 KiB: [ks 0..15][1024B A-fragment]

    const int g    = blockIdx.x & 7;     // group: batch rows 16g..16g+15
    const int m    = blockIdx.x >> 3;    // member: h dims 32m..32m+31
    const int tid  = threadIdx.x;
    const int lane = tid & 63;
    const int w    = tid >> 6;           // wave 0/1: j half-tile

    // ---- W_hh slice -> registers (B-fragment order), one-time ----
    // B-frag lane l, k-step ks: W[q][j = w*16 + (l&15)][k = ks*32 + (l>>4)*8 + e]
    short8 Wr[3][16];
    {
        const int jrow = m * 32 + w * 16 + (lane & 15);
        const int kofs = (lane >> 4) * 8;
#pragma unroll
        for (int q = 0; q < 3; ++q) {
            const float* wrow = Whh + ((size_t)(q * HH + jrow)) * HH + kofs;
#pragma unroll
            for (int ks = 0; ks < 16; ++ks) {
                float4 v0 = *(const float4*)(wrow + ks * 32);
                float4 v1 = *(const float4*)(wrow + ks * 32 + 4);
                union { short8 s; unsigned int u[4]; } pk;
                pk.u[0] = (unsigned int)f2bf(v0.x) | ((unsigned int)f2bf(v0.y) << 16);
                pk.u[1] = (unsigned int)f2bf(v0.z) | ((unsigned int)f2bf(v0.w) << 16);
                pk.u[2] = (unsigned int)f2bf(v1.x) | ((unsigned int)f2bf(v1.y) << 16);
                pk.u[3] = (unsigned int)f2bf(v1.z) | ((unsigned int)f2bf(v1.w) << 16);
                Wr[q][ks] = pk.s;
            }
        }
    }

    const int jj = m * 32 + w * 16 + (lane & 15);   // this lane's global j
    const float bhr = bhh[jj];
    const float bhz = bhh[HH + jj];
    const float bhn = bhh[2 * HH + jj];
    const int b0 = (lane >> 4) * 4;                 // first of 4 batch rows

    float hh[4] = {0.0f, 0.0f, 0.0f, 0.0f};        // carried fp32 state

    // poll/stage mapping: widx = i*128 + tid, i = 0..31
    //   e2 = widx&3, row = (widx>>2)&15, lg = (widx>>6)&3, ks = (widx>>8)&15
    //   src pair = ks*16 + lg*4 + e2 ; dst uint32 = ks*256 + lg*64 + row*4 + e2
    // (consecutive lanes span (row,e2) -> all 32 LDS banks, conflict-free)
    const unsigned char* hA = (const unsigned char*)hF + lane * 16;

    for (int t = 0; t < TT; ++t) {
        // ---- xg prefetch (latency hides under poll) ----
        const unsigned short* xp = xg + ((size_t)t * BB + g * 16) * G3 + jj;
        float xr[4], xz[4], xn[4];
#pragma unroll
        for (int i = 0; i < 4; ++i) {
            const unsigned short* p = xp + (size_t)(b0 + i) * G3;
            xr[i] = bf2f(p[0]); xz[i] = bf2f(p[HH]); xn[i] = bf2f(p[2 * HH]);
        }

        // ---- poll tagged h words (data IS the flag) ----
        const unsigned long long want = (unsigned long long)t;
        const unsigned long long* src = hb64 + ((size_t)(t & 1) * BB + (size_t)g * 16) * 256;
        unsigned long long v[32];
        while (true) {
            bool ok = true;
#pragma unroll
            for (int i = 0; i < 32; ++i) {
                int widx = i * NTH2 + tid;
                int e2 = widx & 3, row = (widx >> 2) & 15;
                int lg = (widx >> 6) & 3, ks = (widx >> 8) & 15;
                int pair = ks * 16 + lg * 4 + e2;
                v[i] = __hip_atomic_load(&src[(size_t)row * 256 + pair],
                                         __ATOMIC_RELAXED, __HIP_MEMORY_SCOPE_AGENT);
                ok &= ((v[i] >> 32) == want);
            }
            if (ok) break;
        }
        // ---- stage to LDS in A-fragment order (conflict-free) ----
#pragma unroll
        for (int i = 0; i < 32; ++i) {
            int widx = i * NTH2 + tid;
            int e2 = widx & 3, row = (widx >> 2) & 15;
            int lg = (widx >> 6) & 3, ks = (widx >> 8) & 15;
            hF[ks * 256 + lg * 64 + row * 4 + e2] = (unsigned int)v[i];
        }
        __syncthreads();   // (1) h tile staged

        // ---- MFMA: 3 gates x K=512, B operands from registers ----
        f32x4 aR = (f32x4)(0.0f), aZ = (f32x4)(0.0f), aN = (f32x4)(0.0f);
#pragma unroll
        for (int ks = 0; ks < 16; ++ks) {
            short8 a = *(const short8*)(hA + ks * 1024);
            aR = __builtin_amdgcn_mfma_f32_16x16x32_bf16(a, Wr[0][ks], aR, 0, 0, 0);
            aZ = __builtin_amdgcn_mfma_f32_16x16x32_bf16(a, Wr[1][ks], aZ, 0, 0, 0);
            aN = __builtin_amdgcn_mfma_f32_16x16x32_bf16(a, Wr[2][ks], aN, 0, 0, 0);
        }
        __syncthreads();   // (2) ds_reads done; next stage may overwrite hF

        // ---- gates in-register; tagged stores (after barrier: no drain on path) ----
        const unsigned long long tag = ((unsigned long long)(t + 1)) << 32;
        unsigned long long* dst = hb64 + (size_t)((t + 1) & 1) * BB * 256;
#pragma unroll
        for (int i = 0; i < 4; ++i) {
            float r = sigmoidf_fast(xr[i] + aR[i] + bhr);
            float z = sigmoidf_fast(xz[i] + aZ[i] + bhz);
            float n = tanhf_fast(xn[i] + r * (aN[i] + bhn));
            hh[i] = (1.0f - z) * n + z * hh[i];
            unsigned int u  = (unsigned int)f2bf(hh[i]);
            unsigned int pv = (unsigned int)__shfl_xor((int)u, 1);
            if ((lane & 1) == 0) {
                unsigned long long word = tag | (unsigned long long)(u | (pv << 16));
                __hip_atomic_store(&dst[(size_t)(g * 16 + b0 + i) * 256 + (jj >> 1)], word,
                                   __ATOMIC_RELAXED, __HIP_MEMORY_SCOPE_AGENT);
            }
            if (t == TT - 1)
                out[(size_t)(g * 16 + b0 + i) * HH + jj] = hh[i];
        }
    }
}

// ---------------------------------------------------------------------------
extern "C" void kernel_launch(void* const* d_in, const int* in_sizes, int n_in,
                              void* d_out, int out_size, void* d_ws, size_t ws_size,
                              hipStream_t stream) {
    const float* x   = (const float*)d_in[0];
    const float* Wih = (const float*)d_in[1];
    const float* Whh = (const float*)d_in[2];
    const float* bih = (const float*)d_in[3];
    const float* bhh = (const float*)d_in[4];
    float* out = (float*)d_out;

    const size_t XG_BYTES   = (size_t)TT * BB * G3 * 2;        // 192 MiB bf16
    unsigned short* xg      = (unsigned short*)d_ws;
    unsigned long long* hb64 = (unsigned long long*)((char*)d_ws + XG_BYTES);
    const size_t HBUF_BYTES = (size_t)2 * BB * 256 * 8;        // 512 KiB tagged pairs

    // tags must start at 0 (= h(0) valid, value 0)
    hipMemsetAsync((char*)d_ws + XG_BYTES, 0, HBUF_BYTES, stream);

    dim3 g1(G3 / 128, TT);
    xgate_gemm<<<g1, 256, 0, stream>>>(x, Wih, bih, xg);

    gru_scan<<<128, NTH2, 0, stream>>>(xg, Whh, bhh, out, hb64);
}